// Round 1
// baseline (900.381 us; speedup 1.0000x reference)
//
#include <hip/hip_runtime.h>
#include <hip/hip_bf16.h>

#define N_NODES 100000
#define E_EDGES 1000000
#define TE 64
#define LDA 136   // padded LDS row stride (bf16 elems): 272B = 17*16B, bank-rotating

typedef __attribute__((ext_vector_type(8))) short bf16x8;
typedef __attribute__((ext_vector_type(4))) float f32x4;

__device__ __forceinline__ short f2bf(float f) {
    unsigned int x = __float_as_uint(f);
    unsigned int r = (x + 0x7fffu + ((x >> 16) & 1u)) >> 16;
    return (short)r;
}

// ---------------- weight pre-pack: f32 [K][N] -> bf16 MFMA B-fragments ----------
// fragment (nt, ks): 64 lanes x 8 bf16, lane l slot j  <- W[ks*32 + 8*(l>>4)+j][nt*16 + (l&15)]
// packed element index = (nt*KS + ks)*512 + l*8 + j
__global__ void pack_weights_kernel(const float* __restrict__ Wt,
                                    const float* __restrict__ Win,
                                    const float* __restrict__ W1,
                                    const float* __restrict__ W2,
                                    short* __restrict__ ws)
{
    int gid = blockIdx.x * 256 + threadIdx.x;
    const float* src; int K, Nw, local; short* dst;
    if      (gid <  32768) { src = Wt;  K = 128; Nw = 256; local = gid;          dst = ws;         }
    else if (gid <  81920) { src = Win; K = 384; Nw = 128; local = gid -  32768; dst = ws + 32768; }
    else if (gid <  98304) { src = W1;  K = 128; Nw = 128; local = gid -  81920; dst = ws + 81920; }
    else if (gid < 100352) { src = W2;  K = 128; Nw =   4; local = gid -  98304; dst = ws + 98304; }
    else return;
    int KS     = K >> 5;
    int frag   = local >> 9;
    int within = local & 511;
    int l  = within >> 3, j = within & 7;
    int nt = frag / KS,  ks = frag - nt * KS;
    int k  = ks * 32 + ((l >> 4) << 3) + j;
    int n  = nt * 16 + (l & 15);
    float v = (n < Nw) ? src[k * Nw + n] : 0.0f;   // zero-pad W2 cols 4..15
    dst[local] = f2bf(v);
}

// ---------------- fused edge kernel -------------------------------------------
__global__ __launch_bounds__(256)
void edge_kernel(const float* __restrict__ h,
                 const float* __restrict__ pos,
                 const float* __restrict__ ea,
                 const float* __restrict__ dst_f,
                 const float* __restrict__ temb,
                 const float* __restrict__ adj,
                 const float* __restrict__ btime,
                 const float* __restrict__ bin,
                 const float* __restrict__ b1,
                 const float* __restrict__ cscale,
                 const int*   __restrict__ ei,
                 const short* __restrict__ ws,
                 float* __restrict__ out)
{
    __shared__ short Abuf[TE * LDA];
    __shared__ short Ybuf[TE * LDA];
    __shared__ int   sIr[TE];
    __shared__ int   sIc[TE];
    __shared__ float sCd[3][TE];
    __shared__ float sAdj[3][TE];

    const int tid = threadIdx.x;
    const int w   = tid >> 6;
    const int l   = tid & 63;
    const int ln  = l & 15;
    const int lg  = l >> 4;
    const int e0  = blockIdx.x * TE;

    // ---- phase 0: per-edge indices, normalized coord diff, adj weights ----
    if (tid < TE) {
        int e  = e0 + tid;
        int ir = ei[e];
        int ic = ei[E_EDGES + e];
        sIr[tid] = ir;
        sIc[tid] = ic;
        float dx = pos[ir*3+0] - pos[ic*3+0];
        float dy = pos[ir*3+1] - pos[ic*3+1];
        float dz = pos[ir*3+2] - pos[ic*3+2];
        float nrm = sqrtf(dx*dx + dy*dy + dz*dz);
        float s = cscale[0] / fmaxf(nrm, 1e-8f);
        sCd[0][tid] = dx * s;
        sCd[1][tid] = dy * s;
        sCd[2][tid] = dz * s;
        sAdj[0][tid] = adj[e*3+0];
        sAdj[1][tid] = adj[e*3+1];
        sAdj[2][tid] = adj[e*3+2];
    }

    // ---- stage tt = silu(time_emb[e]) into Abuf (bf16) ----
    {
        const float* base = temb + (long)e0 * 128;
        #pragma unroll
        for (int it = 0; it < 8; ++it) {
            int i  = tid + 256 * it;
            int r  = i >> 5;
            int c4 = (i & 31) << 2;
            float4 v = *reinterpret_cast<const float4*>(base + r*128 + c4);
            short* d = &Abuf[r*LDA + c4];
            d[0] = f2bf(v.x / (1.f + __expf(-v.x)));
            d[1] = f2bf(v.y / (1.f + __expf(-v.y)));
            d[2] = f2bf(v.z / (1.f + __expf(-v.z)));
            d[3] = f2bf(v.w / (1.f + __expf(-v.w)));
        }
    }
    __syncthreads();

    const int arow = (w << 4) + ln;     // MFMA A-operand row for this lane
    const int acb  = lg << 3;           // k sub-offset within a 32-wide k-step
    const bf16x8* wtP  = reinterpret_cast<const bf16x8*>(ws);          // W_time: 16nt x 4ks
    const bf16x8* winP = reinterpret_cast<const bf16x8*>(ws + 32768);  // W_in:    8nt x 12ks
    const bf16x8* w1P  = reinterpret_cast<const bf16x8*>(ws + 81920);  // W1:      8nt x 4ks
    const bf16x8* w2P  = reinterpret_cast<const bf16x8*>(ws + 98304);  // W2pad:   1nt x 4ks

    // ---- T = tt @ W_time : per-wave 16 rows x 256 cols ----
    f32x4 accT[16];
    #pragma unroll
    for (int i = 0; i < 16; ++i) accT[i] = (f32x4){0.f,0.f,0.f,0.f};
    #pragma unroll
    for (int ks = 0; ks < 4; ++ks) {
        bf16x8 a = *reinterpret_cast<const bf16x8*>(&Abuf[arow*LDA + (ks<<5) + acb]);
        #pragma unroll
        for (int nt = 0; nt < 16; ++nt) {
            bf16x8 b = wtP[((nt<<2) + ks)*64 + l];
            accT[nt] = __builtin_amdgcn_mfma_f32_16x16x32_bf16(a, b, accT[nt], 0, 0, 0);
        }
    }
    __syncthreads();

    // ---- x = h_input @ W_in, staged in 3 K-segments of 128 ----
    f32x4 accX[8];
    #pragma unroll
    for (int i = 0; i < 8; ++i) accX[i] = (f32x4){0.f,0.f,0.f,0.f};

    for (int seg = 0; seg < 3; ++seg) {
        #pragma unroll
        for (int it = 0; it < 8; ++it) {
            int i  = tid + 256 * it;
            int r  = i >> 5;
            int c4 = (i & 31) << 2;
            const float* p;
            if      (seg == 0) p = h + (long)sIr[r] * 128 + c4;
            else if (seg == 1) p = h + (long)sIc[r] * 128 + c4;
            else p = (c4 < 64) ? (ea    + (long)(e0 + r) * 64 + c4)
                               : (dst_f + (long)(e0 + r) * 64 + (c4 - 64));
            float4 v = *reinterpret_cast<const float4*>(p);
            short* d = &Abuf[r*LDA + c4];
            d[0] = f2bf(v.x); d[1] = f2bf(v.y); d[2] = f2bf(v.z); d[3] = f2bf(v.w);
        }
        __syncthreads();
        #pragma unroll
        for (int ks = 0; ks < 4; ++ks) {
            bf16x8 a = *reinterpret_cast<const bf16x8*>(&Abuf[arow*LDA + (ks<<5) + acb]);
            int ksg = (seg << 2) + ks;
            #pragma unroll
            for (int nt = 0; nt < 8; ++nt) {
                bf16x8 b = winP[(nt*12 + ksg)*64 + l];
                accX[nt] = __builtin_amdgcn_mfma_f32_16x16x32_bf16(a, b, accX[nt], 0, 0, 0);
            }
        }
        __syncthreads();
    }

    // ---- +b_in, LayerNorm over 128 cols (rows live in a 16-lane quarter-group) ----
    #pragma unroll
    for (int nt = 0; nt < 8; ++nt) {
        float bv = bin[(nt<<4) + ln];
        #pragma unroll
        for (int r = 0; r < 4; ++r) accX[nt][r] += bv;
    }
    #pragma unroll
    for (int r = 0; r < 4; ++r) {
        float p = 0.f, q = 0.f;
        #pragma unroll
        for (int nt = 0; nt < 8; ++nt) { float x = accX[nt][r]; p += x; q += x*x; }
        #pragma unroll
        for (int d2 = 1; d2 < 16; d2 <<= 1) { p += __shfl_xor(p, d2); q += __shfl_xor(q, d2); }
        float mean = p * 0.0078125f;
        float var  = q * 0.0078125f - mean * mean;
        float rstd = rsqrtf(var + 1e-6f);
        #pragma unroll
        for (int nt = 0; nt < 8; ++nt)
            accX[nt][r] = (accX[nt][r] - mean) * rstd;
    }
    // ---- FiLM modulate: x*(1+scale)+shift  (shift = T[:,0:128], scale = T[:,128:256]) ----
    #pragma unroll
    for (int nt = 0; nt < 8; ++nt) {
        float bsh = btime[(nt<<4) + ln];
        float bsc = btime[128 + (nt<<4) + ln];
        #pragma unroll
        for (int r = 0; r < 4; ++r) {
            float sh = accT[nt][r]     + bsh;
            float sc = accT[nt + 8][r] + bsc;
            accX[nt][r] = accX[nt][r] * (1.f + sc) + sh;
        }
    }
    // ---- write inv (bf16) back to Abuf for next GEMM ----
    {
        int orow = (w << 4) + (lg << 2);
        #pragma unroll
        for (int r = 0; r < 4; ++r)
            #pragma unroll
            for (int nt = 0; nt < 8; ++nt)
                Abuf[(orow + r)*LDA + (nt<<4) + ln] = f2bf(accX[nt][r]);
    }
    __syncthreads();

    // ---- y = silu(inv @ W1 + b1) ----
    f32x4 accY[8];
    #pragma unroll
    for (int i = 0; i < 8; ++i) accY[i] = (f32x4){0.f,0.f,0.f,0.f};
    #pragma unroll
    for (int ks = 0; ks < 4; ++ks) {
        bf16x8 a = *reinterpret_cast<const bf16x8*>(&Abuf[arow*LDA + (ks<<5) + acb]);
        #pragma unroll
        for (int nt = 0; nt < 8; ++nt) {
            bf16x8 b = w1P[((nt<<2) + ks)*64 + l];
            accY[nt] = __builtin_amdgcn_mfma_f32_16x16x32_bf16(a, b, accY[nt], 0, 0, 0);
        }
    }
    {
        int orow = (w << 4) + (lg << 2);
        #pragma unroll
        for (int nt = 0; nt < 8; ++nt) {
            float bv = b1[(nt<<4) + ln];
            #pragma unroll
            for (int r = 0; r < 4; ++r) {
                float x = accY[nt][r] + bv;
                x = x / (1.f + __expf(-x));
                Ybuf[(orow + r)*LDA + (nt<<4) + ln] = f2bf(x);
            }
        }
    }
    __syncthreads();

    // ---- z = tanh(y @ W2) ; per-edge scalar ; atomic scatter ----
    f32x4 accZ = (f32x4){0.f,0.f,0.f,0.f};
    #pragma unroll
    for (int ks = 0; ks < 4; ++ks) {
        bf16x8 a = *reinterpret_cast<const bf16x8*>(&Ybuf[arow*LDA + (ks<<5) + acb]);
        bf16x8 b = w2P[ks*64 + l];
        accZ = __builtin_amdgcn_mfma_f32_16x16x32_bf16(a, b, accZ, 0, 0, 0);
    }
    #pragma unroll
    for (int r = 0; r < 4; ++r) {
        int   m = (w << 4) + (lg << 2) + r;   // edge within block
        float z = tanhf(accZ[r]);
        float wt = (ln == 0) ? 1.0f : ((ln < 4) ? sAdj[ln - 1][m] : 0.0f);
        float v = z * wt;
        v += __shfl_xor(v, 1);
        v += __shfl_xor(v, 2);
        v += __shfl_xor(v, 4);
        v += __shfl_xor(v, 8);
        float s = v * 0.25f;                  // mean over 4 heads
        if (ln < 3) {
            atomicAdd(&out[(long)sIr[m]*3 + ln], sCd[ln][m] * s);
        }
    }
}

extern "C" void kernel_launch(void* const* d_in, const int* in_sizes, int n_in,
                              void* d_out, int out_size, void* d_ws, size_t ws_size,
                              hipStream_t stream) {
    const float* h     = (const float*)d_in[0];
    const float* pos   = (const float*)d_in[1];
    const float* ea    = (const float*)d_in[2];
    const float* dist  = (const float*)d_in[3];
    const float* temb  = (const float*)d_in[4];
    const float* adj   = (const float*)d_in[5];
    const float* Wt    = (const float*)d_in[6];
    const float* bt    = (const float*)d_in[7];
    const float* Win   = (const float*)d_in[8];
    const float* bin   = (const float*)d_in[9];
    const float* W1    = (const float*)d_in[10];
    const float* b1    = (const float*)d_in[11];
    const float* W2    = (const float*)d_in[12];
    const float* cs    = (const float*)d_in[13];
    const int*   ei    = (const int*)d_in[14];
    float*       out   = (float*)d_out;
    short*       ws    = (short*)d_ws;

    // 1) pack weights to bf16 fragment order (100352 elems)
    pack_weights_kernel<<<(100352 + 255) / 256, 256, 0, stream>>>(Wt, Win, W1, W2, ws);
    // 2) out = pos
    hipMemcpyAsync(out, pos, (size_t)out_size * sizeof(float),
                   hipMemcpyDeviceToDevice, stream);
    // 3) fused edge update + atomic segment-sum into out
    edge_kernel<<<E_EDGES / TE, 256, 0, stream>>>(h, pos, ea, dist, temb, adj,
                                                  bt, bin, b1, cs, ei, ws, out);
}